// Round 10
// baseline (130.062 us; speedup 1.0000x reference)
//
#include <hip/hip_runtime.h>
#include <hip/hip_fp16.h>

#define IN_DIM 128
#define HID 16
#define BSHIFT 8                 // bucket = dst >> 8  (256 nodes per bucket)
#define BMASK  255
#define BCAP   9216              // bucket capacity: mean 8192 + 11 sigma
#define PCH    4096              // edges per place-block
#define PTHR   512               // place threads
#define EPT    (PCH / PTHR)      // 8 edges cached per thread

// ---------------------------------------------------------------------------
// Init: zero bucket cursors + edge-index dtype probe (int64 vs int32).
// ---------------------------------------------------------------------------
__global__ void init_kernel(const unsigned int* ei, int* flag, int* gcursor, int NB) {
    int tid = blockIdx.x * blockDim.x + threadIdx.x;
    if (tid < NB) gcursor[tid] = 0;
    if (tid == 0) {
        int zeros = 0;
        for (int j = 0; j < 8; ++j)
            if (ei[2 * j + 1] == 0u) zeros++;
        *flag = (zeros >= 7) ? 1 : 0;  // int64 little-endian => high dwords 0
    }
}

__device__ __forceinline__ int edge_at(const void* ei, long long idx, int is64) {
    if (is64) return (int)((const long long*)ei)[idx];
    return ((const int*)ei)[idx];
}

// ---------------------------------------------------------------------------
// Bin edges into fixed-capacity buckets. Loads BATCHED into register arrays
// (is64 hoisted block-uniform, tail-block guard block-uniform) so the 16
// loads issue back-to-back instead of serializing on the LDS-atomic chain
// (r9: VGPR=20 showed the compiler kept the chain rolled).
// ---------------------------------------------------------------------------
__global__ __launch_bounds__(PTHR) void place_kernel(const void* ei, long long E,
        int* gcursor, unsigned int* __restrict__ binned, int NB, const int* flag) {
    __shared__ int cnt[512];
    __shared__ int wbase[512];
    int tid = threadIdx.x;
    for (int i = tid; i < NB; i += PTHR) cnt[i] = 0;
    __syncthreads();
    const int is64 = *flag;
    const long long e0 = (long long)blockIdx.x * PCH;

    int sA[EPT], dA[EPT];
    if (e0 + PCH <= E) {                       // full block: unguarded batch
        if (is64) {
            const long long* p = (const long long*)ei;
#pragma unroll
            for (int j = 0; j < EPT; ++j) sA[j] = (int)p[e0 + j * PTHR + tid];
#pragma unroll
            for (int j = 0; j < EPT; ++j) dA[j] = (int)p[E + e0 + j * PTHR + tid];
        } else {
            const int* p = (const int*)ei;
#pragma unroll
            for (int j = 0; j < EPT; ++j) sA[j] = p[e0 + j * PTHR + tid];
#pragma unroll
            for (int j = 0; j < EPT; ++j) dA[j] = p[E + e0 + j * PTHR + tid];
        }
    } else {                                   // tail block: per-lane guard
#pragma unroll
        for (int j = 0; j < EPT; ++j) {
            long long e = e0 + j * PTHR + tid;
            bool ok = e < E;
            sA[j] = ok ? edge_at(ei, e, is64) : 0;
            dA[j] = ok ? edge_at(ei, E + e, is64) : -256;   // b -> -1, skipped
        }
    }

    unsigned int v[EPT];
    unsigned int br[EPT];
#pragma unroll
    for (int j = 0; j < EPT; ++j) {
        int b = dA[j] >> BSHIFT;
        bool ok = dA[j] >= 0;
        int r = ok ? atomicAdd(&cnt[b], 1) : 0;
        v[j]  = ((unsigned int)sA[j] << BSHIFT) | (unsigned int)(dA[j] & BMASK);
        br[j] = ok ? (((unsigned int)b << 16) | (unsigned int)r) : 0xFFFFFFFFu;
    }
    __syncthreads();
    for (int i = tid; i < NB; i += PTHR) {
        int c = cnt[i];
        wbase[i] = c ? atomicAdd(&gcursor[i], c) : 0;
    }
    __syncthreads();
#pragma unroll
    for (int j = 0; j < EPT; ++j) {
        if (br[j] != 0xFFFFFFFFu) {
            int b = (int)(br[j] >> 16);
            int r = (int)(br[j] & 0xFFFFu);
            int w = wbase[b] + r;
            if (w < BCAP)                          // defensive; never in practice
                binned[(size_t)b * BCAP + w] = v[j];
        }
    }
}

// ---------------------------------------------------------------------------
// One block (1024 thr) per bucket: LDS per-node count -> rowb/rowe/dis,
// then LDS-ranked scatter of src ids into padded csr.
// ---------------------------------------------------------------------------
__global__ __launch_bounds__(1024) void build_kernel(
        const unsigned int* __restrict__ binned, const int* __restrict__ gtotal,
        int* __restrict__ csr, int* __restrict__ rowb, int* __restrict__ rowe,
        float* __restrict__ dis, int N) {
    __shared__ int cnt[256];
    __shared__ int rowloc[256];
    int b = blockIdx.x, tid = threadIdx.x;
    int base = b * BCAP;
    int total = gtotal[b]; if (total > BCAP) total = BCAP;
    if (tid < 256) cnt[tid] = 0;
    __syncthreads();
    for (int e = tid; e < total; e += 1024)
        atomicAdd(&cnt[binned[(size_t)base + e] & BMASK], 1);
    __syncthreads();
    int c = (tid < 256) ? cnt[tid] : 0;
    if (tid < 256) rowloc[tid] = c;
    __syncthreads();
    for (int off = 1; off < 256; off <<= 1) {          // inclusive scan
        int t_ = (tid < 256 && tid >= off) ? rowloc[tid - off] : 0;
        __syncthreads();
        if (tid < 256) rowloc[tid] += t_;
        __syncthreads();
    }
    if (tid < 256) {
        int excl = rowloc[tid] - c;
        int node = (b << BSHIFT) + tid;
        if (node < N) {
            rowb[node] = base + excl;
            rowe[node] = base + excl + c;
            dis[node] = rsqrtf((float)(c + 1));        // +1 self loop
        }
        cnt[tid] = base + excl;                        // absolute cursors
    }
    __syncthreads();
    for (int e = tid; e < total; e += 1024) {
        unsigned int vv = binned[(size_t)base + e];
        int pos = atomicAdd(&cnt[vv & BMASK], 1);
        csr[pos] = (int)(vv >> BSHIFT);
    }
}

// ---------------------------------------------------------------------------
// ts = fp16( dis * (x @ W1^T) )  [N,16].  64 nodes/block, wave w owns k-slice
// [32w,32w+32): W1 wave-uniform (scalar loads), x -> registers, LDS reduce.
// ---------------------------------------------------------------------------
__global__ __launch_bounds__(256) void gemm1_kernel(
        const float* __restrict__ x, const float* __restrict__ W1,
        const float* __restrict__ dis, __half2* __restrict__ ts, int N) {
    __shared__ float red[4 * 64 * 17];
    const int tid = threadIdx.x;
    const int lane = tid & 63;
    const int wv = tid >> 6;
    const int wq = __builtin_amdgcn_readfirstlane(wv);   // wave-uniform k-quarter
    const int n = blockIdx.x * 64 + lane;

    float acc[HID];
#pragma unroll
    for (int o = 0; o < HID; ++o) acc[o] = 0.f;

    if (n < N) {
        const float* xp = &x[(size_t)n * IN_DIM + wq * 32];
        float4 xv[8];
#pragma unroll
        for (int j = 0; j < 8; ++j) xv[j] = ((const float4*)xp)[j];
        const float* wp = &W1[wq * 32];
#pragma unroll
        for (int kk = 0; kk < 32; ++kk) {
            float xs = ((const float*)xv)[kk];
#pragma unroll
            for (int o = 0; o < HID; ++o)
                acc[o] = fmaf(xs, wp[(size_t)o * IN_DIM + kk], acc[o]);
        }
    }
#pragma unroll
    for (int o = 0; o < HID; ++o)
        red[(wv * 64 + lane) * 17 + o] = acc[o];
    __syncthreads();

    const int nl = tid >> 2;
    const int og = (tid & 3) * 4;
    const int nn = blockIdx.x * 64 + nl;
    if (nn < N) {
        float s0 = 0.f, s1 = 0.f, s2 = 0.f, s3 = 0.f;
#pragma unroll
        for (int w2 = 0; w2 < 4; ++w2) {
            const float* rp = &red[(w2 * 64 + nl) * 17 + og];
            s0 += rp[0]; s1 += rp[1]; s2 += rp[2]; s3 += rp[3];
        }
        float di = dis[nn];
        __half2 p0 = __floats2half2_rn(di * s0, di * s1);
        __half2 p1 = __floats2half2_rn(di * s2, di * s3);
        float2 pk;
        pk.x = *(float*)&p0;
        pk.y = *(float*)&p1;
        ((float2*)ts)[(size_t)nn * 4 + (tid & 3)] = pk;
    }
}

// ---------------------------------------------------------------------------
// Layer-1 gather + bias + ReLU + (.W2) fused. 2 lanes/node, 16B float4 ts
// loads per lane (halves VMEM lane-slots vs 8-lane version), 4-deep batches.
// ---------------------------------------------------------------------------
__global__ __launch_bounds__(256) void gather1_kernel(
        const int* __restrict__ rowb, const int* __restrict__ rowe,
        const int* __restrict__ csr, const __half2* __restrict__ ts,
        const float* __restrict__ dis, const float* __restrict__ b1,
        const float* __restrict__ W2, float* __restrict__ zs, int N) {
    long long gid = (long long)blockIdx.x * blockDim.x + threadIdx.x;
    int i = (int)(gid >> 1);
    int q = (int)(gid & 1);
    if (i >= N) return;
    int beg = rowb[i], end = rowe[i];

    float s[8];
    {   // self loop: 8 halfs = one float4
        float4 sv = *(const float4*)&ts[(size_t)i * 8 + q * 4];
        const __half2* sh = (const __half2*)&sv;
#pragma unroll
        for (int j = 0; j < 4; ++j) {
            float2 f = __half22float2(sh[j]);
            s[2 * j] = f.x; s[2 * j + 1] = f.y;
        }
    }
    int e = beg;
    for (; e + 3 < end; e += 4) {
        int ix[4];
#pragma unroll
        for (int j = 0; j < 4; ++j) ix[j] = csr[e + j];
        float4 tv[4];
#pragma unroll
        for (int j = 0; j < 4; ++j)
            tv[j] = *(const float4*)&ts[(size_t)ix[j] * 8 + q * 4];
#pragma unroll
        for (int j = 0; j < 4; ++j) {
            const __half2* hh = (const __half2*)&tv[j];
#pragma unroll
            for (int k = 0; k < 4; ++k) {
                float2 f = __half22float2(hh[k]);
                s[2 * k] += f.x; s[2 * k + 1] += f.y;
            }
        }
    }
    for (; e < end; ++e) {
        float4 tv = *(const float4*)&ts[(size_t)csr[e] * 8 + q * 4];
        const __half2* hh = (const __half2*)&tv;
#pragma unroll
        for (int k = 0; k < 4; ++k) {
            float2 f = __half22float2(hh[k]);
            s[2 * k] += f.x; s[2 * k + 1] += f.y;
        }
    }
    float di = dis[i];
    float part = 0.f;
#pragma unroll
    for (int j = 0; j < 8; ++j) {
        float h = fmaxf(fmaf(di, s[j], b1[8 * q + j]), 0.f);
        part = fmaf(h, W2[8 * q + j], part);
    }
    part += __shfl_xor(part, 1);
    if (q == 0) zs[i] = di * part;
}

// ---------------------------------------------------------------------------
// Layer-2 gather fused with epilogue: out[i] = dis[i]*(sum zs[src] + zs[i]) + b2
// ---------------------------------------------------------------------------
__global__ __launch_bounds__(256) void gather2_kernel(
        const int* __restrict__ rowb, const int* __restrict__ rowe,
        const int* __restrict__ csr, const float* __restrict__ zs,
        const float* __restrict__ dis, const float* __restrict__ b2,
        float* __restrict__ out, int N) {
    long long gid = (long long)blockIdx.x * blockDim.x + threadIdx.x;
    int i = (int)(gid >> 2);
    int q = (int)(gid & 3);
    if (i >= N) return;
    int beg = rowb[i], end = rowe[i];
    float s = 0.f;
    for (int e = beg + q; e < end; e += 4) s += zs[csr[e]];
    s += __shfl_xor(s, 1);
    s += __shfl_xor(s, 2);
    if (q == 0) out[i] = fmaf(dis[i], s + zs[i], b2[0]);
}

// ---------------------------------------------------------------------------
extern "C" void kernel_launch(void* const* d_in, const int* in_sizes, int n_in,
                              void* d_out, int out_size, void* d_ws, size_t ws_size,
                              hipStream_t stream) {
    const float* x  = (const float*)d_in[0];
    const void*  ei = d_in[1];
    const float* W1 = (const float*)d_in[2];
    const float* b1 = (const float*)d_in[3];
    const float* W2 = (const float*)d_in[4];
    const float* b2 = (const float*)d_in[5];
    float* out = (float*)d_out;

    const int N = in_sizes[0] / IN_DIM;
    const long long E = in_sizes[1] / 2;
    const int NB = (N + BMASK) >> BSHIFT;      // buckets of 256 nodes (<=512)

    char* w = (char*)d_ws;
    // binned (NB*BCAP u32) is dead before gemm1 writes ts (N*16 f16): alias.
    size_t binBytes = (size_t)NB * BCAP * sizeof(unsigned int);
    size_t tsBytes  = (size_t)N * HID * sizeof(__half);
    size_t sharedA  = binBytes > tsBytes ? binBytes : tsBytes;
    unsigned int* binned = (unsigned int*)w;
    __half2*      ts     = (__half2*)w;        w += sharedA;
    int*   csr    = (int*)w;    w += (size_t)NB * BCAP * sizeof(int);
    float* zs     = (float*)w;  w += (size_t)N * sizeof(float);
    float* dis    = (float*)w;  w += (size_t)N * sizeof(float);
    int*   rowb   = (int*)w;    w += (size_t)N * sizeof(int);
    int*   rowe   = (int*)w;    w += (size_t)N * sizeof(int);
    int*   gcursor= (int*)w;    w += 2048 * sizeof(int);
    int*   flag   = (int*)w;

    init_kernel<<<(NB + 255) / 256, 256, 0, stream>>>(
        (const unsigned int*)ei, flag, gcursor, NB);

    int pblk = (int)((E + PCH - 1) / PCH);
    place_kernel<<<pblk, PTHR, 0, stream>>>(ei, E, gcursor, binned, NB, flag);

    build_kernel<<<NB, 1024, 0, stream>>>(binned, gcursor, csr, rowb, rowe, dis, N);

    int gblk = (N + 63) / 64;
    gemm1_kernel<<<gblk, 256, 0, stream>>>(x, W1, dis, ts, N);

    long long g1 = (long long)N * 2;
    gather1_kernel<<<(int)((g1 + 255) / 256), 256, 0, stream>>>(
        rowb, rowe, csr, ts, dis, b1, W2, zs, N);

    long long g2 = (long long)N * 4;
    gather2_kernel<<<(int)((g2 + 255) / 256), 256, 0, stream>>>(
        rowb, rowe, csr, zs, dis, b2, out, N);
}

// Round 11
// 124.162 us; speedup vs baseline: 1.0475x; 1.0475x over previous
//
#include <hip/hip_runtime.h>
#include <hip/hip_fp16.h>

#define IN_DIM 128
#define HID 16
#define BSHIFT 8                 // bucket = dst >> 8  (256 nodes per bucket)
#define BMASK  255
#define BCAP   9216              // bucket capacity: mean 8192 + 11 sigma
#define PCH    4096              // edges per place-block
#define PTHR   512               // place threads
#define EPT    (PCH / PTHR)      // 8 edges cached per thread

// ---------------------------------------------------------------------------
// Init: zero both cursor arrays + edge-index dtype probe (int64 vs int32).
// ---------------------------------------------------------------------------
__global__ void init_kernel(const unsigned int* ei, int* flag,
                            int* gcurA, int* gcurB, int NB) {
    int tid = blockIdx.x * blockDim.x + threadIdx.x;
    if (tid < NB) { gcurA[tid] = 0; gcurB[tid] = 0; }
    if (tid == 0) {
        int zeros = 0;
        for (int j = 0; j < 8; ++j)
            if (ei[2 * j + 1] == 0u) zeros++;
        *flag = (zeros >= 7) ? 1 : 0;  // int64 little-endian => high dwords 0
    }
}

__device__ __forceinline__ int edge_at(const void* ei, long long idx, int is64) {
    if (is64) return (int)((const long long*)ei)[idx];
    return ((const int*)ei)[idx];
}

// ---------------------------------------------------------------------------
// Bin edges into fixed-capacity buckets. BIDIRECTIONAL allocation: even
// blocks take cursor A (bottom-up), odd blocks cursor B (top-down) -- halves
// the serialized RMW chain per cursor address (r9 theory: 782 RMWs x ~100cyc
// = the 40us). Capacity bound cA+cB <= BCAP is unchanged.
// ---------------------------------------------------------------------------
__global__ __launch_bounds__(PTHR) void place_kernel(const void* ei, long long E,
        int* gcurA, int* gcurB, unsigned int* __restrict__ binned, int NB,
        const int* flag) {
    __shared__ int cnt[512];
    __shared__ int wbase[512];
    int tid = threadIdx.x;
    for (int i = tid; i < NB; i += PTHR) cnt[i] = 0;
    __syncthreads();
    const int is64 = *flag;
    const long long e0 = (long long)blockIdx.x * PCH;

    int sA[EPT], dA[EPT];
    if (e0 + PCH <= E) {                       // full block: unguarded batch
        if (is64) {
            const long long* p = (const long long*)ei;
#pragma unroll
            for (int j = 0; j < EPT; ++j) sA[j] = (int)p[e0 + j * PTHR + tid];
#pragma unroll
            for (int j = 0; j < EPT; ++j) dA[j] = (int)p[E + e0 + j * PTHR + tid];
        } else {
            const int* p = (const int*)ei;
#pragma unroll
            for (int j = 0; j < EPT; ++j) sA[j] = p[e0 + j * PTHR + tid];
#pragma unroll
            for (int j = 0; j < EPT; ++j) dA[j] = p[E + e0 + j * PTHR + tid];
        }
    } else {                                   // tail block: per-lane guard
#pragma unroll
        for (int j = 0; j < EPT; ++j) {
            long long e = e0 + j * PTHR + tid;
            bool ok = e < E;
            sA[j] = ok ? edge_at(ei, e, is64) : 0;
            dA[j] = ok ? edge_at(ei, E + e, is64) : -256;   // b -> -1, skipped
        }
    }

    unsigned int v[EPT];
    unsigned int br[EPT];
#pragma unroll
    for (int j = 0; j < EPT; ++j) {
        int b = dA[j] >> BSHIFT;
        bool ok = dA[j] >= 0;
        int r = ok ? atomicAdd(&cnt[b], 1) : 0;
        v[j]  = ((unsigned int)sA[j] << BSHIFT) | (unsigned int)(dA[j] & BMASK);
        br[j] = ok ? (((unsigned int)b << 16) | (unsigned int)r) : 0xFFFFFFFFu;
    }
    __syncthreads();
    const bool rev = (blockIdx.x & 1);
    int* gc = rev ? gcurB : gcurA;
    for (int i = tid; i < NB; i += PTHR) {
        int c = cnt[i];
        wbase[i] = c ? atomicAdd(&gc[i], c) : 0;
    }
    __syncthreads();
#pragma unroll
    for (int j = 0; j < EPT; ++j) {
        if (br[j] != 0xFFFFFFFFu) {
            int b = (int)(br[j] >> 16);
            int r = (int)(br[j] & 0xFFFFu);
            int w = wbase[b] + r;
            if (w < BCAP) {                        // defensive; never in practice
                size_t pos = rev ? ((size_t)b * BCAP + (BCAP - 1 - w))
                                 : ((size_t)b * BCAP + w);
                binned[pos] = v[j];
            }
        }
    }
}

// ---------------------------------------------------------------------------
// One block (1024 thr) per bucket: LDS per-node count over BOTH segments ->
// rowb/rowe/dis, then LDS-ranked scatter of src ids into packed csr.
// ---------------------------------------------------------------------------
__global__ __launch_bounds__(1024) void build_kernel(
        const unsigned int* __restrict__ binned, const int* __restrict__ gtotA,
        const int* __restrict__ gtotB, int* __restrict__ csr,
        int* __restrict__ rowb, int* __restrict__ rowe,
        float* __restrict__ dis, int N) {
    __shared__ int cnt[256];
    __shared__ int rowloc[256];
    int b = blockIdx.x, tid = threadIdx.x;
    int base = b * BCAP;
    int cA = gtotA[b]; if (cA > BCAP) cA = BCAP;
    int cB = gtotB[b]; if (cB > BCAP - cA) cB = BCAP - cA;   // defensive
    if (tid < 256) cnt[tid] = 0;
    __syncthreads();
    for (int e = tid; e < cA; e += 1024)
        atomicAdd(&cnt[binned[(size_t)base + e] & BMASK], 1);
    for (int e = tid; e < cB; e += 1024)
        atomicAdd(&cnt[binned[(size_t)base + BCAP - 1 - e] & BMASK], 1);
    __syncthreads();
    int c = (tid < 256) ? cnt[tid] : 0;
    if (tid < 256) rowloc[tid] = c;
    __syncthreads();
    for (int off = 1; off < 256; off <<= 1) {          // inclusive scan
        int t_ = (tid < 256 && tid >= off) ? rowloc[tid - off] : 0;
        __syncthreads();
        if (tid < 256) rowloc[tid] += t_;
        __syncthreads();
    }
    if (tid < 256) {
        int excl = rowloc[tid] - c;
        int node = (b << BSHIFT) + tid;
        if (node < N) {
            rowb[node] = base + excl;
            rowe[node] = base + excl + c;
            dis[node] = rsqrtf((float)(c + 1));        // +1 self loop
        }
        cnt[tid] = base + excl;                        // absolute cursors
    }
    __syncthreads();
    for (int e = tid; e < cA; e += 1024) {
        unsigned int vv = binned[(size_t)base + e];
        int pos = atomicAdd(&cnt[vv & BMASK], 1);
        csr[pos] = (int)(vv >> BSHIFT);
    }
    for (int e = tid; e < cB; e += 1024) {
        unsigned int vv = binned[(size_t)base + BCAP - 1 - e];
        int pos = atomicAdd(&cnt[vv & BMASK], 1);
        csr[pos] = (int)(vv >> BSHIFT);
    }
}

// ---------------------------------------------------------------------------
// ts = fp16( dis * (x @ W1^T) )  [N,16].  64 nodes/block, wave w owns k-slice
// [32w,32w+32): W1 wave-uniform (scalar loads), x -> registers, LDS reduce.
// ---------------------------------------------------------------------------
__global__ __launch_bounds__(256) void gemm1_kernel(
        const float* __restrict__ x, const float* __restrict__ W1,
        const float* __restrict__ dis, __half2* __restrict__ ts, int N) {
    __shared__ float red[4 * 64 * 17];
    const int tid = threadIdx.x;
    const int lane = tid & 63;
    const int wv = tid >> 6;
    const int wq = __builtin_amdgcn_readfirstlane(wv);   // wave-uniform k-quarter
    const int n = blockIdx.x * 64 + lane;

    float acc[HID];
#pragma unroll
    for (int o = 0; o < HID; ++o) acc[o] = 0.f;

    if (n < N) {
        const float* xp = &x[(size_t)n * IN_DIM + wq * 32];
        float4 xv[8];
#pragma unroll
        for (int j = 0; j < 8; ++j) xv[j] = ((const float4*)xp)[j];
        const float* wp = &W1[wq * 32];
#pragma unroll
        for (int kk = 0; kk < 32; ++kk) {
            float xs = ((const float*)xv)[kk];
#pragma unroll
            for (int o = 0; o < HID; ++o)
                acc[o] = fmaf(xs, wp[(size_t)o * IN_DIM + kk], acc[o]);
        }
    }
#pragma unroll
    for (int o = 0; o < HID; ++o)
        red[(wv * 64 + lane) * 17 + o] = acc[o];
    __syncthreads();

    const int nl = tid >> 2;
    const int og = (tid & 3) * 4;
    const int nn = blockIdx.x * 64 + nl;
    if (nn < N) {
        float s0 = 0.f, s1 = 0.f, s2 = 0.f, s3 = 0.f;
#pragma unroll
        for (int w2 = 0; w2 < 4; ++w2) {
            const float* rp = &red[(w2 * 64 + nl) * 17 + og];
            s0 += rp[0]; s1 += rp[1]; s2 += rp[2]; s3 += rp[3];
        }
        float di = dis[nn];
        __half2 p0 = __floats2half2_rn(di * s0, di * s1);
        __half2 p1 = __floats2half2_rn(di * s2, di * s3);
        float2 pk;
        pk.x = *(float*)&p0;
        pk.y = *(float*)&p1;
        ((float2*)ts)[(size_t)nn * 4 + (tid & 3)] = pk;
    }
}

// ---------------------------------------------------------------------------
// Layer-1 gather + MLP fused. 4 lanes/node, EDGE-split: lane q owns edges
// e = beg+q, +4, ... and loads the FULL 32B ts row (2 x float4) -> 3 VMEM
// lane-slots/edge, no redundant csr loads, 400K threads of TLP.
// ---------------------------------------------------------------------------
__global__ __launch_bounds__(256) void gather1_kernel(
        const int* __restrict__ rowb, const int* __restrict__ rowe,
        const int* __restrict__ csr, const float4* __restrict__ tsf,
        const float* __restrict__ dis, const float* __restrict__ b1,
        const float* __restrict__ W2, float* __restrict__ zs, int N) {
    long long gid = (long long)blockIdx.x * blockDim.x + threadIdx.x;
    int i = (int)(gid >> 2);
    int q = (int)(gid & 3);
    if (i >= N) return;

    float s[16];
#pragma unroll
    for (int j = 0; j < 16; ++j) s[j] = 0.f;

    if (q == 0) {   // self loop handled by lane 0
        float4 a = tsf[(size_t)i * 2], b = tsf[(size_t)i * 2 + 1];
        const __half2* ha = (const __half2*)&a;
        const __half2* hb = (const __half2*)&b;
#pragma unroll
        for (int k = 0; k < 4; ++k) {
            float2 f = __half22float2(ha[k]);
            s[2 * k] = f.x; s[2 * k + 1] = f.y;
        }
#pragma unroll
        for (int k = 0; k < 4; ++k) {
            float2 f = __half22float2(hb[k]);
            s[8 + 2 * k] = f.x; s[8 + 2 * k + 1] = f.y;
        }
    }
    int end = rowe[i];
    for (int e = rowb[i] + q; e < end; e += 4) {
        int src = csr[e];
        float4 a = tsf[(size_t)src * 2], b = tsf[(size_t)src * 2 + 1];
        const __half2* ha = (const __half2*)&a;
        const __half2* hb = (const __half2*)&b;
#pragma unroll
        for (int k = 0; k < 4; ++k) {
            float2 f = __half22float2(ha[k]);
            s[2 * k] += f.x; s[2 * k + 1] += f.y;
        }
#pragma unroll
        for (int k = 0; k < 4; ++k) {
            float2 f = __half22float2(hb[k]);
            s[8 + 2 * k] += f.x; s[8 + 2 * k + 1] += f.y;
        }
    }
    // reduce the 16 partials across the 4 lanes of this node
#pragma unroll
    for (int j = 0; j < 16; ++j) {
        s[j] += __shfl_xor(s[j], 1);
        s[j] += __shfl_xor(s[j], 2);
    }
    if (q == 0) {
        float di = dis[i];
        float part = 0.f;
#pragma unroll
        for (int j = 0; j < 16; ++j) {
            float h = fmaxf(fmaf(di, s[j], b1[j]), 0.f);
            part = fmaf(h, W2[j], part);
        }
        zs[i] = di * part;
    }
}

// ---------------------------------------------------------------------------
// Layer-2 gather fused with epilogue: out[i] = dis[i]*(sum zs[src] + zs[i]) + b2
// ---------------------------------------------------------------------------
__global__ __launch_bounds__(256) void gather2_kernel(
        const int* __restrict__ rowb, const int* __restrict__ rowe,
        const int* __restrict__ csr, const float* __restrict__ zs,
        const float* __restrict__ dis, const float* __restrict__ b2,
        float* __restrict__ out, int N) {
    long long gid = (long long)blockIdx.x * blockDim.x + threadIdx.x;
    int i = (int)(gid >> 2);
    int q = (int)(gid & 3);
    if (i >= N) return;
    int beg = rowb[i], end = rowe[i];
    float s = 0.f;
    for (int e = beg + q; e < end; e += 4) s += zs[csr[e]];
    s += __shfl_xor(s, 1);
    s += __shfl_xor(s, 2);
    if (q == 0) out[i] = fmaf(dis[i], s + zs[i], b2[0]);
}

// ---------------------------------------------------------------------------
extern "C" void kernel_launch(void* const* d_in, const int* in_sizes, int n_in,
                              void* d_out, int out_size, void* d_ws, size_t ws_size,
                              hipStream_t stream) {
    const float* x  = (const float*)d_in[0];
    const void*  ei = d_in[1];
    const float* W1 = (const float*)d_in[2];
    const float* b1 = (const float*)d_in[3];
    const float* W2 = (const float*)d_in[4];
    const float* b2 = (const float*)d_in[5];
    float* out = (float*)d_out;

    const int N = in_sizes[0] / IN_DIM;
    const long long E = in_sizes[1] / 2;
    const int NB = (N + BMASK) >> BSHIFT;      // buckets of 256 nodes (<=512)

    char* w = (char*)d_ws;
    // binned (NB*BCAP u32) is dead before gemm1 writes ts (N*16 f16): alias.
    size_t binBytes = (size_t)NB * BCAP * sizeof(unsigned int);
    size_t tsBytes  = (size_t)N * HID * sizeof(__half);
    size_t sharedA  = binBytes > tsBytes ? binBytes : tsBytes;
    unsigned int* binned = (unsigned int*)w;
    __half2*      ts     = (__half2*)w;        w += sharedA;
    int*   csr    = (int*)w;    w += (size_t)NB * BCAP * sizeof(int);
    float* zs     = (float*)w;  w += (size_t)N * sizeof(float);
    float* dis    = (float*)w;  w += (size_t)N * sizeof(float);
    int*   rowb   = (int*)w;    w += (size_t)N * sizeof(int);
    int*   rowe   = (int*)w;    w += (size_t)N * sizeof(int);
    int*   gcurA  = (int*)w;    w += 1024 * sizeof(int);
    int*   gcurB  = (int*)w;    w += 1024 * sizeof(int);
    int*   flag   = (int*)w;

    init_kernel<<<(NB + 255) / 256, 256, 0, stream>>>(
        (const unsigned int*)ei, flag, gcurA, gcurB, NB);

    int pblk = (int)((E + PCH - 1) / PCH);
    place_kernel<<<pblk, PTHR, 0, stream>>>(ei, E, gcurA, gcurB, binned, NB, flag);

    build_kernel<<<NB, 1024, 0, stream>>>(binned, gcurA, gcurB, csr, rowb, rowe, dis, N);

    int gblk = (N + 63) / 64;
    gemm1_kernel<<<gblk, 256, 0, stream>>>(x, W1, dis, ts, N);

    long long g1 = (long long)N * 4;
    gather1_kernel<<<(int)((g1 + 255) / 256), 256, 0, stream>>>(
        rowb, rowe, csr, (const float4*)ts, dis, b1, W2, zs, N);

    long long g2 = (long long)N * 4;
    gather2_kernel<<<(int)((g2 + 255) / 256), 256, 0, stream>>>(
        rowb, rowe, csr, zs, dis, b2, out, N);
}

// Round 12
// 98.020 us; speedup vs baseline: 1.3269x; 1.2667x over previous
//
#include <hip/hip_runtime.h>
#include <hip/hip_fp16.h>

#define IN_DIM 128
#define HID 16
#define BSHIFT 8                 // bucket = dst >> 8  (256 nodes per bucket)
#define BMASK  255
#define BCAP   9216              // bucket capacity: mean 8192 + 11 sigma
#define PCH    4096              // edges per place-block
#define PTHR   512               // place threads
#define EPT    (PCH / PTHR)      // 8 edges cached per thread
#define TSCALE 4096.0f           // ts fixed-point scale (2^12)
#define ZSCALE 262144.0f         // zs fixed-point scale (2^18)

// ---------------------------------------------------------------------------
// Init: zero both cursor arrays + edge-index dtype probe (int64 vs int32).
// ---------------------------------------------------------------------------
__global__ void init_kernel(const unsigned int* ei, int* flag,
                            int* gcurA, int* gcurB, int NB) {
    int tid = blockIdx.x * blockDim.x + threadIdx.x;
    if (tid < NB) { gcurA[tid] = 0; gcurB[tid] = 0; }
    if (tid == 0) {
        int zeros = 0;
        for (int j = 0; j < 8; ++j)
            if (ei[2 * j + 1] == 0u) zeros++;
        *flag = (zeros >= 7) ? 1 : 0;  // int64 little-endian => high dwords 0
    }
}

__device__ __forceinline__ int edge_at(const void* ei, long long idx, int is64) {
    if (is64) return (int)((const long long*)ei)[idx];
    return ((const int*)ei)[idx];
}

// ---------------------------------------------------------------------------
// Bin edges into fixed-capacity buckets. Bidirectional allocation (even
// blocks bottom-up via gcurA, odd top-down via gcurB) halves the serialized
// RMW chain per cursor address. cA+cB <= BCAP unchanged.
// ---------------------------------------------------------------------------
__global__ __launch_bounds__(PTHR) void place_kernel(const void* ei, long long E,
        int* gcurA, int* gcurB, unsigned int* __restrict__ binned, int NB,
        const int* flag) {
    __shared__ int cnt[512];
    __shared__ int wbase[512];
    int tid = threadIdx.x;
    for (int i = tid; i < NB; i += PTHR) cnt[i] = 0;
    __syncthreads();
    const int is64 = *flag;
    const long long e0 = (long long)blockIdx.x * PCH;

    int sA[EPT], dA[EPT];
    if (e0 + PCH <= E) {                       // full block: unguarded batch
        if (is64) {
            const long long* p = (const long long*)ei;
#pragma unroll
            for (int j = 0; j < EPT; ++j) sA[j] = (int)p[e0 + j * PTHR + tid];
#pragma unroll
            for (int j = 0; j < EPT; ++j) dA[j] = (int)p[E + e0 + j * PTHR + tid];
        } else {
            const int* p = (const int*)ei;
#pragma unroll
            for (int j = 0; j < EPT; ++j) sA[j] = p[e0 + j * PTHR + tid];
#pragma unroll
            for (int j = 0; j < EPT; ++j) dA[j] = p[E + e0 + j * PTHR + tid];
        }
    } else {                                   // tail block: per-lane guard
#pragma unroll
        for (int j = 0; j < EPT; ++j) {
            long long e = e0 + j * PTHR + tid;
            bool ok = e < E;
            sA[j] = ok ? edge_at(ei, e, is64) : 0;
            dA[j] = ok ? edge_at(ei, E + e, is64) : -256;   // b -> -1, skipped
        }
    }

    unsigned int v[EPT];
    unsigned int br[EPT];
#pragma unroll
    for (int j = 0; j < EPT; ++j) {
        int b = dA[j] >> BSHIFT;
        bool ok = dA[j] >= 0;
        int r = ok ? atomicAdd(&cnt[b], 1) : 0;
        v[j]  = ((unsigned int)sA[j] << BSHIFT) | (unsigned int)(dA[j] & BMASK);
        br[j] = ok ? (((unsigned int)b << 16) | (unsigned int)r) : 0xFFFFFFFFu;
    }
    __syncthreads();
    const bool rev = (blockIdx.x & 1);
    int* gc = rev ? gcurB : gcurA;
    for (int i = tid; i < NB; i += PTHR) {
        int c = cnt[i];
        wbase[i] = c ? atomicAdd(&gc[i], c) : 0;
    }
    __syncthreads();
#pragma unroll
    for (int j = 0; j < EPT; ++j) {
        if (br[j] != 0xFFFFFFFFu) {
            int b = (int)(br[j] >> 16);
            int r = (int)(br[j] & 0xFFFFu);
            int w = wbase[b] + r;
            if (w < BCAP) {                        // defensive; never in practice
                size_t pos = rev ? ((size_t)b * BCAP + (BCAP - 1 - w))
                                 : ((size_t)b * BCAP + w);
                binned[pos] = v[j];
            }
        }
    }
}

// ---------------------------------------------------------------------------
// Per-node degree -> dis, straight from binned (both segments).
// LDS INT atomics only (proven-fast ds_add_u32 path, build r4-r11).
// ---------------------------------------------------------------------------
__global__ __launch_bounds__(1024) void degdis_kernel(
        const unsigned int* __restrict__ binned, const int* __restrict__ gtotA,
        const int* __restrict__ gtotB, float* __restrict__ dis, int N) {
    __shared__ int cnt[256];
    int b = blockIdx.x, tid = threadIdx.x;
    int base = b * BCAP;
    int cA = gtotA[b]; if (cA > BCAP) cA = BCAP;
    int cB = gtotB[b]; if (cB > BCAP - cA) cB = BCAP - cA;
    if (tid < 256) cnt[tid] = 0;
    __syncthreads();
    for (int e = tid; e < cA; e += 1024)
        atomicAdd(&cnt[binned[(size_t)base + e] & BMASK], 1);
    for (int e = tid; e < cB; e += 1024)
        atomicAdd(&cnt[binned[(size_t)base + BCAP - 1 - e] & BMASK], 1);
    __syncthreads();
    if (tid < 256) {
        int node = (b << BSHIFT) + tid;
        if (node < N) dis[node] = rsqrtf((float)(cnt[tid] + 1));  // +1 self loop
    }
}

// ---------------------------------------------------------------------------
// ts16 = int16( dis * (x @ W1^T) * 2^12 )  [N,16]. 64 nodes/block, wave w
// owns k-quarter; W1 wave-uniform scalar loads; LDS cross-wave reduce.
// ---------------------------------------------------------------------------
__global__ __launch_bounds__(256) void gemm1_kernel(
        const float* __restrict__ x, const float* __restrict__ W1,
        const float* __restrict__ dis, short* __restrict__ ts16, int N) {
    __shared__ float red[4 * 64 * 17];
    const int tid = threadIdx.x;
    const int lane = tid & 63;
    const int wv = tid >> 6;
    const int wq = __builtin_amdgcn_readfirstlane(wv);   // wave-uniform k-quarter
    const int n = blockIdx.x * 64 + lane;

    float acc[HID];
#pragma unroll
    for (int o = 0; o < HID; ++o) acc[o] = 0.f;

    if (n < N) {
        const float* xp = &x[(size_t)n * IN_DIM + wq * 32];
        float4 xv[8];
#pragma unroll
        for (int j = 0; j < 8; ++j) xv[j] = ((const float4*)xp)[j];
        const float* wp = &W1[wq * 32];
#pragma unroll
        for (int kk = 0; kk < 32; ++kk) {
            float xs = ((const float*)xv)[kk];
#pragma unroll
            for (int o = 0; o < HID; ++o)
                acc[o] = fmaf(xs, wp[(size_t)o * IN_DIM + kk], acc[o]);
        }
    }
#pragma unroll
    for (int o = 0; o < HID; ++o)
        red[(wv * 64 + lane) * 17 + o] = acc[o];
    __syncthreads();

    const int nl = tid >> 2;
    const int og = (tid & 3) * 4;
    const int nn = blockIdx.x * 64 + nl;
    if (nn < N) {
        float s0 = 0.f, s1 = 0.f, s2 = 0.f, s3 = 0.f;
#pragma unroll
        for (int w2 = 0; w2 < 4; ++w2) {
            const float* rp = &red[(w2 * 64 + nl) * 17 + og];
            s0 += rp[0]; s1 += rp[1]; s2 += rp[2]; s3 += rp[3];
        }
        float di = dis[nn] * TSCALE;
        int i0 = (int)rintf(fminf(fmaxf(di * s0, -32767.f), 32767.f));
        int i1 = (int)rintf(fminf(fmaxf(di * s1, -32767.f), 32767.f));
        int i2 = (int)rintf(fminf(fmaxf(di * s2, -32767.f), 32767.f));
        int i3 = (int)rintf(fminf(fmaxf(di * s3, -32767.f), 32767.f));
        uint2 pk;
        pk.x = ((unsigned int)i0 & 0xFFFFu) | ((unsigned int)i1 << 16);
        pk.y = ((unsigned int)i2 & 0xFFFFu) | ((unsigned int)i3 << 16);
        ((uint2*)ts16)[(size_t)nn * 4 + (tid & 3)] = pk;
    }
}

// ---------------------------------------------------------------------------
// Layer-1 aggregation DIRECT from binned. INT32 LDS accumulators (ds_add_u32
// -- the proven-fast path; r8's failure was fp32 LDS atomics -> CAS loop).
// Epilogue: self-loop + bias + ReLU + (.W2) -> zs. No CSR, no build.
// ---------------------------------------------------------------------------
__global__ __launch_bounds__(1024) void agg1_kernel(
        const unsigned int* __restrict__ binned, const int* __restrict__ gtotA,
        const int* __restrict__ gtotB, const short* __restrict__ ts16,
        const float* __restrict__ dis, const float* __restrict__ b1,
        const float* __restrict__ W2, float* __restrict__ zs, int N) {
    __shared__ int acc[256 * 17];
    int b = blockIdx.x, tid = threadIdx.x;
    for (int i = tid; i < 256 * 17; i += 1024) acc[i] = 0;
    __syncthreads();
    int base = b * BCAP;
    int cA = gtotA[b]; if (cA > BCAP) cA = BCAP;
    int cB = gtotB[b]; if (cB > BCAP - cA) cB = BCAP - cA;

#define AGG1_EDGE(IDX)                                                        \
    {                                                                         \
        unsigned int v = binned[(size_t)base + (IDX)];                        \
        int src = (int)(v >> BSHIFT);                                         \
        int row = (int)(v & BMASK) * 17;                                      \
        const int4* tp = (const int4*)(ts16 + (size_t)src * 16);              \
        int4 a = tp[0], c = tp[1];                                            \
        atomicAdd(&acc[row + 0],  (int)(short)(a.x & 0xFFFF));                \
        atomicAdd(&acc[row + 1],  a.x >> 16);                                 \
        atomicAdd(&acc[row + 2],  (int)(short)(a.y & 0xFFFF));                \
        atomicAdd(&acc[row + 3],  a.y >> 16);                                 \
        atomicAdd(&acc[row + 4],  (int)(short)(a.z & 0xFFFF));                \
        atomicAdd(&acc[row + 5],  a.z >> 16);                                 \
        atomicAdd(&acc[row + 6],  (int)(short)(a.w & 0xFFFF));                \
        atomicAdd(&acc[row + 7],  a.w >> 16);                                 \
        atomicAdd(&acc[row + 8],  (int)(short)(c.x & 0xFFFF));                \
        atomicAdd(&acc[row + 9],  c.x >> 16);                                 \
        atomicAdd(&acc[row + 10], (int)(short)(c.y & 0xFFFF));                \
        atomicAdd(&acc[row + 11], c.y >> 16);                                 \
        atomicAdd(&acc[row + 12], (int)(short)(c.z & 0xFFFF));                \
        atomicAdd(&acc[row + 13], c.z >> 16);                                 \
        atomicAdd(&acc[row + 14], (int)(short)(c.w & 0xFFFF));                \
        atomicAdd(&acc[row + 15], c.w >> 16);                                 \
    }

    for (int e = tid; e < cA; e += 1024) AGG1_EDGE(e)
    for (int e = tid; e < cB; e += 1024) AGG1_EDGE(BCAP - 1 - e)
#undef AGG1_EDGE
    __syncthreads();
    if (tid < 256) {
        int node = (b << BSHIFT) + tid;
        if (node < N) {
            float di = dis[node];
            const int4* tp = (const int4*)(ts16 + (size_t)node * 16);
            int4 a = tp[0], c = tp[1];
            int self[16] = {
                (int)(short)(a.x & 0xFFFF), a.x >> 16,
                (int)(short)(a.y & 0xFFFF), a.y >> 16,
                (int)(short)(a.z & 0xFFFF), a.z >> 16,
                (int)(short)(a.w & 0xFFFF), a.w >> 16,
                (int)(short)(c.x & 0xFFFF), c.x >> 16,
                (int)(short)(c.y & 0xFFFF), c.y >> 16,
                (int)(short)(c.z & 0xFFFF), c.z >> 16,
                (int)(short)(c.w & 0xFFFF), c.w >> 16 };
            float z = 0.f;
#pragma unroll
            for (int j = 0; j < 16; ++j) {
                float s = (float)(acc[tid * 17 + j] + self[j]) * (1.0f / TSCALE);
                float h = fmaxf(fmaf(di, s, b1[j]), 0.f);
                z = fmaf(h, W2[j], z);
            }
            zs[node] = di * z;
        }
    }
}

// ---------------------------------------------------------------------------
// Layer-2 aggregation direct from binned: scalar int LDS acc + fused epilogue.
// ---------------------------------------------------------------------------
__global__ __launch_bounds__(1024) void agg2_kernel(
        const unsigned int* __restrict__ binned, const int* __restrict__ gtotA,
        const int* __restrict__ gtotB, const float* __restrict__ zs,
        const float* __restrict__ dis, const float* __restrict__ b2,
        float* __restrict__ out, int N) {
    __shared__ int acc2[256];
    int b = blockIdx.x, tid = threadIdx.x;
    if (tid < 256) acc2[tid] = 0;
    __syncthreads();
    int base = b * BCAP;
    int cA = gtotA[b]; if (cA > BCAP) cA = BCAP;
    int cB = gtotB[b]; if (cB > BCAP - cA) cB = BCAP - cA;
    for (int e = tid; e < cA; e += 1024) {
        unsigned int v = binned[(size_t)base + e];
        atomicAdd(&acc2[v & BMASK], (int)rintf(zs[v >> BSHIFT] * ZSCALE));
    }
    for (int e = tid; e < cB; e += 1024) {
        unsigned int v = binned[(size_t)base + BCAP - 1 - e];
        atomicAdd(&acc2[v & BMASK], (int)rintf(zs[v >> BSHIFT] * ZSCALE));
    }
    __syncthreads();
    if (tid < 256) {
        int node = (b << BSHIFT) + tid;
        if (node < N) {
            float s = (float)acc2[tid] * (1.0f / ZSCALE) + zs[node];
            out[node] = fmaf(dis[node], s, b2[0]);
        }
    }
}

// ---------------------------------------------------------------------------
extern "C" void kernel_launch(void* const* d_in, const int* in_sizes, int n_in,
                              void* d_out, int out_size, void* d_ws, size_t ws_size,
                              hipStream_t stream) {
    const float* x  = (const float*)d_in[0];
    const void*  ei = d_in[1];
    const float* W1 = (const float*)d_in[2];
    const float* b1 = (const float*)d_in[3];
    const float* W2 = (const float*)d_in[4];
    const float* b2 = (const float*)d_in[5];
    float* out = (float*)d_out;

    const int N = in_sizes[0] / IN_DIM;
    const long long E = in_sizes[1] / 2;
    const int NB = (N + BMASK) >> BSHIFT;      // buckets of 256 nodes (<=512)

    char* w = (char*)d_ws;
    unsigned int* binned = (unsigned int*)w;  w += (size_t)NB * BCAP * sizeof(unsigned int);
    short* ts16   = (short*)w;  w += (size_t)N * HID * sizeof(short);
    float* zs     = (float*)w;  w += (size_t)N * sizeof(float);
    float* dis    = (float*)w;  w += (size_t)N * sizeof(float);
    int*   gcurA  = (int*)w;    w += 1024 * sizeof(int);
    int*   gcurB  = (int*)w;    w += 1024 * sizeof(int);
    int*   flag   = (int*)w;

    init_kernel<<<(NB + 255) / 256, 256, 0, stream>>>(
        (const unsigned int*)ei, flag, gcurA, gcurB, NB);

    int pblk = (int)((E + PCH - 1) / PCH);
    place_kernel<<<pblk, PTHR, 0, stream>>>(ei, E, gcurA, gcurB, binned, NB, flag);

    degdis_kernel<<<NB, 1024, 0, stream>>>(binned, gcurA, gcurB, dis, N);

    int gblk = (N + 63) / 64;
    gemm1_kernel<<<gblk, 256, 0, stream>>>(x, W1, dis, ts16, N);

    agg1_kernel<<<NB, 1024, 0, stream>>>(binned, gcurA, gcurB, ts16, dis, b1, W2, zs, N);

    agg2_kernel<<<NB, 1024, 0, stream>>>(binned, gcurA, gcurB, zs, dis, b2, out, N);
}

// Round 13
// 95.217 us; speedup vs baseline: 1.3660x; 1.0294x over previous
//
#include <hip/hip_runtime.h>

#define IN_DIM 128
#define HID 16
#define BSHIFT 8                 // bucket = dst >> 8  (256 nodes per bucket)
#define BMASK  255
#define BCAP   9216              // bucket capacity
#define MID    4608              // region size (two regions per bucket)
#define PCH    8192              // edges per place-block (halves block count)
#define PTHR   512               // place threads
#define EPT    (PCH / PTHR)      // 16 edges cached per thread
#define TSCALE 4096.0f           // ts fixed-point scale (2^12)
#define ZSCALE 262144.0f         // zs fixed-point scale (2^18)

// ---------------------------------------------------------------------------
// Init: zero 4 cursor arrays + edge-index dtype probe (int64 vs int32).
// ---------------------------------------------------------------------------
__global__ void init_kernel(const unsigned int* ei, int* flag, int* gcur) {
    int tid = blockIdx.x * blockDim.x + threadIdx.x;
    if (tid < 4096) gcur[tid] = 0;
    if (tid == 0) {
        int zeros = 0;
        for (int j = 0; j < 8; ++j)
            if (ei[2 * j + 1] == 0u) zeros++;
        *flag = (zeros >= 7) ? 1 : 0;  // int64 little-endian => high dwords 0
    }
}

__device__ __forceinline__ int edge_at(const void* ei, long long idx, int is64) {
    if (is64) return (int)((const long long*)ei)[idx];
    return ((const int*)ei)[idx];
}

// ---------------------------------------------------------------------------
// Bin edges into fixed-capacity buckets. 4-WAY cursor split: block q=bid&3
// uses cursor set q; regions [0,MID) (q=0 up, q=1 down) and [MID,BCAP)
// (q=2 up, q=3 down). Quarters the per-address RMW chain vs 1 cursor.
// Stored data is contiguous per segment -> consumers read 3 linear ranges.
// ---------------------------------------------------------------------------
__global__ __launch_bounds__(PTHR) void place_kernel(const void* ei, long long E,
        int* gcur, unsigned int* __restrict__ binned, int NB, const int* flag) {
    __shared__ int cnt[512];
    __shared__ int wbase[512];
    int tid = threadIdx.x;
    for (int i = tid; i < NB; i += PTHR) cnt[i] = 0;
    __syncthreads();
    const int is64 = *flag;
    const long long e0 = (long long)blockIdx.x * PCH;

    int sA[EPT], dA[EPT];
    if (e0 + PCH <= E) {                       // full block: unguarded batch
        if (is64) {
            const long long* p = (const long long*)ei;
#pragma unroll
            for (int j = 0; j < EPT; ++j) sA[j] = (int)p[e0 + j * PTHR + tid];
#pragma unroll
            for (int j = 0; j < EPT; ++j) dA[j] = (int)p[E + e0 + j * PTHR + tid];
        } else {
            const int* p = (const int*)ei;
#pragma unroll
            for (int j = 0; j < EPT; ++j) sA[j] = p[e0 + j * PTHR + tid];
#pragma unroll
            for (int j = 0; j < EPT; ++j) dA[j] = p[E + e0 + j * PTHR + tid];
        }
    } else {                                   // tail block: per-lane guard
#pragma unroll
        for (int j = 0; j < EPT; ++j) {
            long long e = e0 + j * PTHR + tid;
            bool ok = e < E;
            sA[j] = ok ? edge_at(ei, e, is64) : 0;
            dA[j] = ok ? edge_at(ei, E + e, is64) : -256;   // b -> -1, skipped
        }
    }

    unsigned int v[EPT];
    unsigned int br[EPT];
#pragma unroll
    for (int j = 0; j < EPT; ++j) {
        int b = dA[j] >> BSHIFT;
        bool ok = dA[j] >= 0;
        int r = ok ? atomicAdd(&cnt[b], 1) : 0;
        v[j]  = ((unsigned int)sA[j] << BSHIFT) | (unsigned int)(dA[j] & BMASK);
        br[j] = ok ? (((unsigned int)b << 16) | (unsigned int)r) : 0xFFFFFFFFu;
    }
    __syncthreads();
    const int q = (int)(blockIdx.x & 3);
    int* gc = gcur + q * 1024;
    for (int i = tid; i < NB; i += PTHR) {
        int c = cnt[i];
        wbase[i] = c ? atomicAdd(&gc[i], c) : 0;
    }
    __syncthreads();
    const int regBase = (q >> 1) * MID;
    const bool down = (q & 1);
#pragma unroll
    for (int j = 0; j < EPT; ++j) {
        if (br[j] != 0xFFFFFFFFu) {
            int b = (int)(br[j] >> 16);
            int r = (int)(br[j] & 0xFFFFu);
            int w = wbase[b] + r;
            if (w < MID) {                         // defensive; never in practice
                int pos = regBase + (down ? (MID - 1 - w) : w);
                binned[(size_t)b * BCAP + pos] = v[j];
            }
        }
    }
}

// ---------------------------------------------------------------------------
// Per-bucket occupied ranges from the 4 cursors (defensive clamps).
// r0 = [0, cA), r1 = [MID-cB, MID+cC), r2 = [BCAP-cD, BCAP)
// ---------------------------------------------------------------------------
__device__ __forceinline__ void bucket_ranges(const int* gcur, int b,
        int& r0hi, int& r1lo, int& r1hi, int& r2lo) {
    int cA = gcur[b];            if (cA > MID) cA = MID;
    int cB = gcur[1024 + b];     if (cB > MID - cA) cB = MID - cA;
    int cC = gcur[2048 + b];     if (cC > MID) cC = MID;
    int cD = gcur[3072 + b];     if (cD > MID - cC) cD = MID - cC;
    r0hi = cA;
    r1lo = MID - cB;
    r1hi = MID + cC;
    r2lo = BCAP - cD;
}

// ---------------------------------------------------------------------------
// Per-node degree -> dis (int LDS atomics, 3 linear ranges).
// ---------------------------------------------------------------------------
__global__ __launch_bounds__(1024) void degdis_kernel(
        const unsigned int* __restrict__ binned, const int* __restrict__ gcur,
        float* __restrict__ dis, int N) {
    __shared__ int cnt[256];
    int b = blockIdx.x, tid = threadIdx.x;
    int base = b * BCAP;
    int r0hi, r1lo, r1hi, r2lo;
    bucket_ranges(gcur, b, r0hi, r1lo, r1hi, r2lo);
    if (tid < 256) cnt[tid] = 0;
    __syncthreads();
    for (int e = tid; e < r0hi; e += 1024)
        atomicAdd(&cnt[binned[(size_t)base + e] & BMASK], 1);
    for (int e = r1lo + tid; e < r1hi; e += 1024)
        atomicAdd(&cnt[binned[(size_t)base + e] & BMASK], 1);
    for (int e = r2lo + tid; e < BCAP; e += 1024)
        atomicAdd(&cnt[binned[(size_t)base + e] & BMASK], 1);
    __syncthreads();
    if (tid < 256) {
        int node = (b << BSHIFT) + tid;
        if (node < N) dis[node] = rsqrtf((float)(cnt[tid] + 1));  // +1 self loop
    }
}

// ---------------------------------------------------------------------------
// ts16 = int16( dis * (x @ W1^T) * 2^12 )  [N,16]. 64 nodes/block, wave w
// owns k-quarter; W1 wave-uniform scalar loads; LDS cross-wave reduce.
// ---------------------------------------------------------------------------
__global__ __launch_bounds__(256) void gemm1_kernel(
        const float* __restrict__ x, const float* __restrict__ W1,
        const float* __restrict__ dis, short* __restrict__ ts16, int N) {
    __shared__ float red[4 * 64 * 17];
    const int tid = threadIdx.x;
    const int lane = tid & 63;
    const int wv = tid >> 6;
    const int wq = __builtin_amdgcn_readfirstlane(wv);   // wave-uniform k-quarter
    const int n = blockIdx.x * 64 + lane;

    float acc[HID];
#pragma unroll
    for (int o = 0; o < HID; ++o) acc[o] = 0.f;

    if (n < N) {
        const float* xp = &x[(size_t)n * IN_DIM + wq * 32];
        float4 xv[8];
#pragma unroll
        for (int j = 0; j < 8; ++j) xv[j] = ((const float4*)xp)[j];
        const float* wp = &W1[wq * 32];
#pragma unroll
        for (int kk = 0; kk < 32; ++kk) {
            float xs = ((const float*)xv)[kk];
#pragma unroll
            for (int o = 0; o < HID; ++o)
                acc[o] = fmaf(xs, wp[(size_t)o * IN_DIM + kk], acc[o]);
        }
    }
#pragma unroll
    for (int o = 0; o < HID; ++o)
        red[(wv * 64 + lane) * 17 + o] = acc[o];
    __syncthreads();

    const int nl = tid >> 2;
    const int og = (tid & 3) * 4;
    const int nn = blockIdx.x * 64 + nl;
    if (nn < N) {
        float s0 = 0.f, s1 = 0.f, s2 = 0.f, s3 = 0.f;
#pragma unroll
        for (int w2 = 0; w2 < 4; ++w2) {
            const float* rp = &red[(w2 * 64 + nl) * 17 + og];
            s0 += rp[0]; s1 += rp[1]; s2 += rp[2]; s3 += rp[3];
        }
        float di = dis[nn] * TSCALE;
        int i0 = (int)rintf(fminf(fmaxf(di * s0, -32767.f), 32767.f));
        int i1 = (int)rintf(fminf(fmaxf(di * s1, -32767.f), 32767.f));
        int i2 = (int)rintf(fminf(fmaxf(di * s2, -32767.f), 32767.f));
        int i3 = (int)rintf(fminf(fmaxf(di * s3, -32767.f), 32767.f));
        uint2 pk;
        pk.x = ((unsigned int)i0 & 0xFFFFu) | ((unsigned int)i1 << 16);
        pk.y = ((unsigned int)i2 & 0xFFFFu) | ((unsigned int)i3 << 16);
        ((uint2*)ts16)[(size_t)nn * 4 + (tid & 3)] = pk;
    }
}

// ---------------------------------------------------------------------------
// Layer-1 aggregation direct from binned: INT32 LDS accumulators, 3 ranges.
// Epilogue: self-loop + bias + ReLU + (.W2) -> zs.
// ---------------------------------------------------------------------------
__global__ __launch_bounds__(1024) void agg1_kernel(
        const unsigned int* __restrict__ binned, const int* __restrict__ gcur,
        const short* __restrict__ ts16, const float* __restrict__ dis,
        const float* __restrict__ b1, const float* __restrict__ W2,
        float* __restrict__ zs, int N) {
    __shared__ int acc[256 * 17];
    int b = blockIdx.x, tid = threadIdx.x;
    for (int i = tid; i < 256 * 17; i += 1024) acc[i] = 0;
    __syncthreads();
    int base = b * BCAP;
    int r0hi, r1lo, r1hi, r2lo;
    bucket_ranges(gcur, b, r0hi, r1lo, r1hi, r2lo);

#define AGG1_EDGE(IDX)                                                        \
    {                                                                         \
        unsigned int v = binned[(size_t)base + (IDX)];                        \
        int src = (int)(v >> BSHIFT);                                         \
        int row = (int)(v & BMASK) * 17;                                      \
        const int4* tp = (const int4*)(ts16 + (size_t)src * 16);              \
        int4 a = tp[0], c = tp[1];                                            \
        atomicAdd(&acc[row + 0],  (int)(short)(a.x & 0xFFFF));                \
        atomicAdd(&acc[row + 1],  a.x >> 16);                                 \
        atomicAdd(&acc[row + 2],  (int)(short)(a.y & 0xFFFF));                \
        atomicAdd(&acc[row + 3],  a.y >> 16);                                 \
        atomicAdd(&acc[row + 4],  (int)(short)(a.z & 0xFFFF));                \
        atomicAdd(&acc[row + 5],  a.z >> 16);                                 \
        atomicAdd(&acc[row + 6],  (int)(short)(a.w & 0xFFFF));                \
        atomicAdd(&acc[row + 7],  a.w >> 16);                                 \
        atomicAdd(&acc[row + 8],  (int)(short)(c.x & 0xFFFF));                \
        atomicAdd(&acc[row + 9],  c.x >> 16);                                 \
        atomicAdd(&acc[row + 10], (int)(short)(c.y & 0xFFFF));                \
        atomicAdd(&acc[row + 11], c.y >> 16);                                 \
        atomicAdd(&acc[row + 12], (int)(short)(c.z & 0xFFFF));                \
        atomicAdd(&acc[row + 13], c.z >> 16);                                 \
        atomicAdd(&acc[row + 14], (int)(short)(c.w & 0xFFFF));                \
        atomicAdd(&acc[row + 15], c.w >> 16);                                 \
    }

    for (int e = tid; e < r0hi; e += 1024) AGG1_EDGE(e)
    for (int e = r1lo + tid; e < r1hi; e += 1024) AGG1_EDGE(e)
    for (int e = r2lo + tid; e < BCAP; e += 1024) AGG1_EDGE(e)
#undef AGG1_EDGE
    __syncthreads();
    if (tid < 256) {
        int node = (b << BSHIFT) + tid;
        if (node < N) {
            float di = dis[node];
            const int4* tp = (const int4*)(ts16 + (size_t)node * 16);
            int4 a = tp[0], c = tp[1];
            int self[16] = {
                (int)(short)(a.x & 0xFFFF), a.x >> 16,
                (int)(short)(a.y & 0xFFFF), a.y >> 16,
                (int)(short)(a.z & 0xFFFF), a.z >> 16,
                (int)(short)(a.w & 0xFFFF), a.w >> 16,
                (int)(short)(c.x & 0xFFFF), c.x >> 16,
                (int)(short)(c.y & 0xFFFF), c.y >> 16,
                (int)(short)(c.z & 0xFFFF), c.z >> 16,
                (int)(short)(c.w & 0xFFFF), c.w >> 16 };
            float z = 0.f;
#pragma unroll
            for (int j = 0; j < 16; ++j) {
                float s = (float)(acc[tid * 17 + j] + self[j]) * (1.0f / TSCALE);
                float h = fmaxf(fmaf(di, s, b1[j]), 0.f);
                z = fmaf(h, W2[j], z);
            }
            zs[node] = di * z;
        }
    }
}

// ---------------------------------------------------------------------------
// Layer-2 aggregation direct from binned: scalar int LDS acc + fused epilogue.
// ---------------------------------------------------------------------------
__global__ __launch_bounds__(1024) void agg2_kernel(
        const unsigned int* __restrict__ binned, const int* __restrict__ gcur,
        const float* __restrict__ zs, const float* __restrict__ dis,
        const float* __restrict__ b2, float* __restrict__ out, int N) {
    __shared__ int acc2[256];
    int b = blockIdx.x, tid = threadIdx.x;
    if (tid < 256) acc2[tid] = 0;
    __syncthreads();
    int base = b * BCAP;
    int r0hi, r1lo, r1hi, r2lo;
    bucket_ranges(gcur, b, r0hi, r1lo, r1hi, r2lo);
    for (int e = tid; e < r0hi; e += 1024) {
        unsigned int v = binned[(size_t)base + e];
        atomicAdd(&acc2[v & BMASK], (int)rintf(zs[v >> BSHIFT] * ZSCALE));
    }
    for (int e = r1lo + tid; e < r1hi; e += 1024) {
        unsigned int v = binned[(size_t)base + e];
        atomicAdd(&acc2[v & BMASK], (int)rintf(zs[v >> BSHIFT] * ZSCALE));
    }
    for (int e = r2lo + tid; e < BCAP; e += 1024) {
        unsigned int v = binned[(size_t)base + e];
        atomicAdd(&acc2[v & BMASK], (int)rintf(zs[v >> BSHIFT] * ZSCALE));
    }
    __syncthreads();
    if (tid < 256) {
        int node = (b << BSHIFT) + tid;
        if (node < N) {
            float s = (float)acc2[tid] * (1.0f / ZSCALE) + zs[node];
            out[node] = fmaf(dis[node], s, b2[0]);
        }
    }
}

// ---------------------------------------------------------------------------
extern "C" void kernel_launch(void* const* d_in, const int* in_sizes, int n_in,
                              void* d_out, int out_size, void* d_ws, size_t ws_size,
                              hipStream_t stream) {
    const float* x  = (const float*)d_in[0];
    const void*  ei = d_in[1];
    const float* W1 = (const float*)d_in[2];
    const float* b1 = (const float*)d_in[3];
    const float* W2 = (const float*)d_in[4];
    const float* b2 = (const float*)d_in[5];
    float* out = (float*)d_out;

    const int N = in_sizes[0] / IN_DIM;
    const long long E = in_sizes[1] / 2;
    const int NB = (N + BMASK) >> BSHIFT;      // buckets of 256 nodes (<=512)

    char* w = (char*)d_ws;
    unsigned int* binned = (unsigned int*)w;  w += (size_t)NB * BCAP * sizeof(unsigned int);
    short* ts16   = (short*)w;  w += (size_t)N * HID * sizeof(short);
    float* zs     = (float*)w;  w += (size_t)N * sizeof(float);
    float* dis    = (float*)w;  w += (size_t)N * sizeof(float);
    int*   gcur   = (int*)w;    w += 4096 * sizeof(int);
    int*   flag   = (int*)w;

    init_kernel<<<16, 256, 0, stream>>>((const unsigned int*)ei, flag, gcur);

    int pblk = (int)((E + PCH - 1) / PCH);
    place_kernel<<<pblk, PTHR, 0, stream>>>(ei, E, gcur, binned, NB, flag);

    degdis_kernel<<<NB, 1024, 0, stream>>>(binned, gcur, dis, N);

    int gblk = (N + 63) / 64;
    gemm1_kernel<<<gblk, 256, 0, stream>>>(x, W1, dis, ts16, N);

    agg1_kernel<<<NB, 1024, 0, stream>>>(binned, gcur, ts16, dis, b1, W2, zs, N);

    agg2_kernel<<<NB, 1024, 0, stream>>>(binned, gcur, zs, dis, b2, out, N);
}